// Round 6
// baseline (49.726 us; speedup 1.0000x reference)
//
#include <hip/hip_runtime.h>
#include <hip/hip_bf16.h>

#define H 2048
#define RIN 2304
#define SW 256
#define SD 200

// ws layout (floats):
#define WS_CDOT 0
#define WS_SDOT 4
#define WS_GH0  260
#define WS_GH1  6404
#define WS_GI0  12548

// out layout (floats): [0..100) logits, [100..2148) h0, [2148..4196) h1,
// [4196..55396) new_stack (200x256)

typedef __attribute__((ext_vector_type(4))) float f32x4;

__device__ __forceinline__ float wave_reduce(float acc) {
  #pragma unroll
  for (int off = 32; off > 0; off >>= 1) acc += __shfl_down(acc, off);
  return acc;  // valid in lane 0
}

__device__ __forceinline__ float sigmoidf(float x) {
  return 1.f / (1.f + expf(-x));
}

// One row x one LDS-resident x: K = nch*256 floats. W loads are 4-deep fenced
// global bursts (pure vmcnt stream); x comes from LDS (lgkmcnt) so the global
// retire queue contains ONLY the W stream. nch = 8 (K=2048) or 16 (K=4096).
__device__ __forceinline__ float row_dot(const float* __restrict__ Wrow,
                                         const f32x4* xl, int nch) {
  int lane = threadIdx.x & 63;
  const f32x4* w4 = (const f32x4*)Wrow + lane;
  const f32x4* x4 = xl + lane;
  f32x4 acc = (f32x4)(0.f);
  for (int g = 0; g < nch; g += 4) {
    f32x4 a0 = w4[g * 64], a1 = w4[g * 64 + 64];
    f32x4 a2 = w4[g * 64 + 128], a3 = w4[g * 64 + 192];
    asm volatile("" : "+v"(a0), "+v"(a1), "+v"(a2), "+v"(a3));
    acc += a0 * x4[g * 64];
    acc += a1 * x4[g * 64 + 64];
    acc += a2 * x4[g * 64 + 128];
    acc += a3 * x4[g * 64 + 192];
  }
  return acc[0] + acc[1] + acc[2] + acc[3];
}

// K1: all input-only matvecs. Block = 8 consecutive rows of one matrix,
// x staged in LDS. Blocks: [0,768) Whh0 ; [768,1536) Whh1 ; [1536,2304)
// Wih0 cols 0..2048 ; [2304,2336) Ws (K=4096) ; 2336 Wc (3 rows, K=4096).
__global__ __launch_bounds__(256)
void k1_matvecs(const float* __restrict__ hidden, const int* __restrict__ inp,
                const float* __restrict__ emb,
                const float* __restrict__ Wc, const float* __restrict__ bc,
                const float* __restrict__ Ws, const float* __restrict__ bs,
                const float* __restrict__ Wih0, const float* __restrict__ bih0,
                const float* __restrict__ Whh0, const float* __restrict__ bhh0,
                const float* __restrict__ Whh1, const float* __restrict__ bhh1,
                float* __restrict__ ws) {
  __shared__ f32x4 xl[1024];  // up to 16 KB of x
  int pb = blockIdx.x;
  int t = threadIdx.x, wv = t >> 6, lane = t & 63;

  const float* W; const float* x; const float* bias; float* dst;
  int base, nch, K4, nrows;
  size_t ld;
  if (pb < 768) {
    W = Whh0; x = hidden;     bias = bhh0; dst = ws + WS_GH0;
    base = pb * 8;            nch = 8;  K4 = 512;  nrows = 8; ld = H;
  } else if (pb < 1536) {
    W = Whh1; x = hidden + H; bias = bhh1; dst = ws + WS_GH1;
    base = (pb - 768) * 8;    nch = 8;  K4 = 512;  nrows = 8; ld = H;
  } else if (pb < 2304) {
    W = Wih0; x = emb + (size_t)inp[0] * H; bias = bih0; dst = ws + WS_GI0;
    base = (pb - 1536) * 8;   nch = 8;  K4 = 512;  nrows = 8; ld = RIN;
  } else if (pb < 2336) {
    W = Ws; x = hidden;       bias = bs;  dst = ws + WS_SDOT;
    base = (pb - 2304) * 8;   nch = 16; K4 = 1024; nrows = 8; ld = 2 * H;
  } else {
    W = Wc; x = hidden;       bias = bc;  dst = ws + WS_CDOT;
    base = 0;                 nch = 16; K4 = 1024; nrows = 3; ld = 2 * H;
  }

  const f32x4* xg = (const f32x4*)x;
  for (int i = t; i < K4; i += 256) xl[i] = xg[i];
  __syncthreads();

  #pragma unroll
  for (int rr = 0; rr < 2; ++rr) {
    int r = wv * 2 + rr;
    if (r >= nrows) break;
    int row = base + r;
    float d = row_dot(W + (size_t)row * ld, xl, nch);
    d = wave_reduce(d);
    if (lane == 0) dst[row] = d + bias[row];
  }
}

// K2: blocks [0,2048): GRU layer0 finish (one j per block; 3 waves do the
//     K=256 stack-column dots of Wih0); blocks [2048,2248): new_stack rows.
__global__ __launch_bounds__(256)
void k2_stack_gru0(const float* __restrict__ stack,
                   const float* __restrict__ hidden,
                   const float* __restrict__ Wih0,
                   const float* __restrict__ ws,
                   float* out) {
  int t = threadIdx.x;
  float c0 = ws[WS_CDOT + 0], c1 = ws[WS_CDOT + 1], c2 = ws[WS_CDOT + 2];
  float m = fmaxf(c0, fmaxf(c1, c2));
  float e0 = expf(c0 - m), e1 = expf(c1 - m), e2 = expf(c2 - m);
  float inv = 1.f / (e0 + e1 + e2);
  float a_push = e0 * inv, a_pop = e1 * inv, a_noop = e2 * inv;

  int b = blockIdx.x;
  if (b >= 2048) {
    int r = b - 2048;
    float up = (r == 0) ? tanhf(ws[WS_SDOT + t]) : stack[(r - 1) * SW + t];
    float down = (r == SD - 1) ? 0.f : stack[(r + 1) * SW + t];
    out[4196 + r * SW + t] = a_noop * stack[r * SW + t] + a_push * up + a_pop * down;
    return;
  }
  __shared__ float st[SW];
  __shared__ float gred[3];
  st[t] = a_noop * stack[t] + a_push * tanhf(ws[WS_SDOT + t]) + a_pop * stack[SW + t];
  __syncthreads();
  int wv = t >> 6, lane = t & 63;
  int j = b;
  if (wv < 3) {
    const f32x4* w4 = (const f32x4*)(Wih0 + (size_t)(wv * H + j) * RIN + H);
    const f32x4* s4 = (const f32x4*)st;
    f32x4 a = w4[lane];
    f32x4 xv = s4[lane];
    f32x4 p = a * xv;
    float acc = wave_reduce(p[0] + p[1] + p[2] + p[3]);
    if (lane == 0) gred[wv] = acc;
  }
  __syncthreads();
  if (t == 0) {
    float gr = ws[WS_GI0 + j] + gred[0] + ws[WS_GH0 + j];
    float gz = ws[WS_GI0 + H + j] + gred[1] + ws[WS_GH0 + H + j];
    float r = sigmoidf(gr);
    float z = sigmoidf(gz);
    float n = tanhf(ws[WS_GI0 + 2 * H + j] + gred[2] + r * ws[WS_GH0 + 2 * H + j]);
    out[100 + j] = (1.f - z) * n + z * hidden[j];
  }
}

// K3: GRU layer1. Block = 8 consecutive j (h0 staged in LDS); wave handles
// 2 j, each = 3 gate rows (j, H+j, 2H+j) + in-wave combine.
// Grid MUST be H/8 = 256 blocks (R5 crash: 768 blocks ran j past H and
// wrote out-of-bounds).
__global__ __launch_bounds__(256)
void k3_gru1(const float* __restrict__ hidden,
             const float* __restrict__ Wih1, const float* __restrict__ bih1,
             const float* __restrict__ ws,
             float* out) {
  __shared__ f32x4 xl[512];
  int pb = blockIdx.x;
  int t = threadIdx.x, wv = t >> 6, lane = t & 63;
  const float* h0 = out + 100;  // written by k2
  const f32x4* h04 = (const f32x4*)h0;
  for (int i = t; i < 512; i += 256) xl[i] = h04[i];
  __syncthreads();

  #pragma unroll
  for (int jj = 0; jj < 2; ++jj) {
    int j = pb * 8 + wv * 2 + jj;
    if (j >= H) break;
    float dr = row_dot(Wih1 + (size_t)j * H, xl, 8);
    float dz = row_dot(Wih1 + (size_t)(H + j) * H, xl, 8);
    float dn = row_dot(Wih1 + (size_t)(2 * H + j) * H, xl, 8);
    dr = wave_reduce(dr);
    dz = wave_reduce(dz);
    dn = wave_reduce(dn);
    if (lane == 0) {
      float r = sigmoidf(dr + bih1[j] + ws[WS_GH1 + j]);
      float z = sigmoidf(dz + bih1[H + j] + ws[WS_GH1 + H + j]);
      float n = tanhf(dn + bih1[2 * H + j] + r * ws[WS_GH1 + 2 * H + j]);
      out[100 + H + j] = (1.f - z) * n + z * hidden[H + j];
    }
  }
}

// K4: logits = Wd @ h1 + bd. 100 rows, h1 staged in LDS. 13 blocks x 8 rows.
__global__ __launch_bounds__(256)
void k4_logits(const float* __restrict__ Wd, const float* __restrict__ bd,
               float* out) {
  __shared__ f32x4 xl[512];
  int pb = blockIdx.x;
  int t = threadIdx.x, wv = t >> 6, lane = t & 63;
  const float* h1 = out + 100 + H;  // written by k3
  const f32x4* h14 = (const f32x4*)h1;
  for (int i = t; i < 512; i += 256) xl[i] = h14[i];
  __syncthreads();

  #pragma unroll
  for (int rr = 0; rr < 2; ++rr) {
    int row = pb * 8 + wv * 2 + rr;
    if (row >= 100) break;
    float d = row_dot(Wd + (size_t)row * H, xl, 8);
    d = wave_reduce(d);
    if (lane == 0) out[row] = d + bd[row];
  }
}

extern "C" void kernel_launch(void* const* d_in, const int* in_sizes, int n_in,
                              void* d_out, int out_size, void* d_ws, size_t ws_size,
                              hipStream_t stream) {
  const int*   inp    = (const int*)d_in[0];
  const float* hidden = (const float*)d_in[1];
  const float* stack  = (const float*)d_in[2];
  const float* emb    = (const float*)d_in[3];
  const float* Wc     = (const float*)d_in[4];
  const float* bc     = (const float*)d_in[5];
  const float* Ws     = (const float*)d_in[6];
  const float* bs     = (const float*)d_in[7];
  const float* Wih0   = (const float*)d_in[8];
  const float* Whh0   = (const float*)d_in[9];
  const float* bih0   = (const float*)d_in[10];
  const float* bhh0   = (const float*)d_in[11];
  const float* Wih1   = (const float*)d_in[12];
  const float* Whh1   = (const float*)d_in[13];
  const float* bih1   = (const float*)d_in[14];
  const float* bhh1   = (const float*)d_in[15];
  const float* Wd     = (const float*)d_in[16];
  const float* bd     = (const float*)d_in[17];
  float* ws  = (float*)d_ws;
  float* out = (float*)d_out;

  k1_matvecs<<<2337, 256, 0, stream>>>(hidden, inp, emb, Wc, bc, Ws, bs,
                                       Wih0, bih0, Whh0, bhh0, Whh1, bhh1, ws);
  k2_stack_gru0<<<2248, 256, 0, stream>>>(stack, hidden, Wih0, ws, out);
  k3_gru1<<<256, 256, 0, stream>>>(hidden, Wih1, bih1, ws, out);
  k4_logits<<<13, 256, 0, stream>>>(Wd, bd, out);
}